// Round 3
// baseline (655.340 us; speedup 1.0000x reference)
//
#include <hip/hip_runtime.h>
#include <hip/hip_bf16.h>
#include <stdint.h>

// compose_lora (fp32 in / fp32 out):
//   out = x@W^T + bias + sum_n (SCALE*w_n) * (x@A_n^T)@B_n^T
// Factored: W_eff = W + sum_n c_n * B_n@A_n  (K=128 MFMA GEMM, bf16),
// then out = x_bf16 @ W_eff^T + bias  (M=8192,N=4096,K=4096, m97 structure).
// Evidence for fp32 I/O: R1 bf16-read => NaN (inputs fp32); R2 bf16-write
// => absmax 8.98 == predicted value for fp32 harness readback of packed
// bf16 ushorts (float[i] ~ out[2i+1], tail zero). Threshold = 2% * max|ref|.

typedef __attribute__((ext_vector_type(4))) float f32x4;
typedef __attribute__((ext_vector_type(8))) __bf16 bf16x8;
typedef __attribute__((ext_vector_type(8))) unsigned short u16x8;

#define GLOBAL_AS(p) ((const __attribute__((address_space(1))) void*)(p))
#define LDS_AS(p)    ((__attribute__((address_space(3))) void*)(p))

__device__ __forceinline__ ushort f2b(float f) {
    __hip_bfloat16 h = __float2bfloat16(f);
    ushort u;
    __builtin_memcpy(&u, &h, 2);
    return u;
}

// ---------------------------------------------------------------------------
// prep: Bcat[o][k] = (2*lw[k/16]) * lora_B[k/16][o][k%16]   (o:4096, k:128)
//       AcatT[d][k] = lora_A[k][d]                           (d:4096, k:128)
// (SCALE = ALPHA/RANK = 2; coef_n = SCALE * lora_weights[n])
// ---------------------------------------------------------------------------
__global__ void prep_kernel(const float* __restrict__ lA,   // [128][4096]
                            const float* __restrict__ lB,   // [8][4096][16]
                            const float* __restrict__ lw,   // [8]
                            ushort* __restrict__ Bcat,      // [4096][128]
                            ushort* __restrict__ AcatT)     // [4096][128]
{
    int idx = blockIdx.x * 256 + threadIdx.x;   // 0..524287 exact
    int o = idx >> 7, k = idx & 127;
    int n = k >> 4, r = k & 15;
    Bcat[idx]  = f2b(2.0f * lw[n] * lB[((size_t)n * 4096 + o) * 16 + r]);
    AcatT[idx] = f2b(lA[(size_t)k * 4096 + o]);   // d == o here
}

// ---------------------------------------------------------------------------
// cvtx: x fp32 -> bf16 workspace copy (2048 elems/block)
// ---------------------------------------------------------------------------
__global__ void cvtx_kernel(const float* __restrict__ x, ushort* __restrict__ xb) {
    size_t i = ((size_t)blockIdx.x * 256 + threadIdx.x) * 8;
    const float4* xf = (const float4*)(x + i);
    float4 a = xf[0], b = xf[1];
    u16x8 r;
    r[0] = f2b(a.x); r[1] = f2b(a.y); r[2] = f2b(a.z); r[3] = f2b(a.w);
    r[4] = f2b(b.x); r[5] = f2b(b.y); r[6] = f2b(b.z); r[7] = f2b(b.w);
    *reinterpret_cast<u16x8*>(xb + i) = r;
}

// ---------------------------------------------------------------------------
// m97-structure bf16 GEMM: Out[M][N] = A[M][K]*B[N][K]^T (+bias[n] / +C[m][n])
// 128x128 tile, BK=32, 4 waves, 4x4 mfma_f32_16x16x32_bf16 per wave.
// aux: ADD_BIAS -> fp32 [N]; ADD_C -> fp32 [M][N]. OUT_F32 picks store type.
// ---------------------------------------------------------------------------
template <bool OUT_F32, bool ADD_BIAS, bool ADD_C>
__global__ __launch_bounds__(256) void gemm_bt(
    const ushort* __restrict__ Amat, const ushort* __restrict__ Bmat,
    const float* __restrict__ aux, void* __restrict__ OutP,
    int M, int N, int K)
{
    constexpr int BM = 128, BN = 128, BK = 32;
    __shared__ __align__(16) ushort As[BM * BK];
    __shared__ __align__(16) ushort Bs[BN * BK];

    const int tid  = threadIdx.x;
    const int lane = tid & 63;
    const int w    = tid >> 6;
    const int wm   = (w >> 1) * 64;
    const int wn   = (w & 1) * 64;
    const int quad = lane >> 4;
    const int lrow = lane & 15;
    const int m0 = blockIdx.x * BM;
    const int n0 = blockIdx.y * BN;

    // staging: wave w fills chunks {2w,2w+1}; lane l -> row 16c+l/4, k=(l%4)*8
    const int srow = (w * 2) * 16 + (lane >> 2);
    const int kofs = (lane & 3) * 8;
    const ushort* agp0 = Amat + (size_t)(m0 + srow) * K + kofs;
    const ushort* agp1 = agp0 + (size_t)16 * K;
    const ushort* bgp0 = Bmat + (size_t)(n0 + srow) * K + kofs;
    const ushort* bgp1 = bgp0 + (size_t)16 * K;
    ushort* lA0 = &As[(w * 2) * 512];
    ushort* lA1 = &As[(w * 2 + 1) * 512];
    ushort* lB0 = &Bs[(w * 2) * 512];
    ushort* lB1 = &Bs[(w * 2 + 1) * 512];

    f32x4 acc[4][4] = {};
    const int nK = K / BK;
    for (int kt = 0; kt < nK; ++kt) {
        __syncthreads();
        __builtin_amdgcn_global_load_lds(GLOBAL_AS(agp0), LDS_AS(lA0), 16, 0, 0);
        __builtin_amdgcn_global_load_lds(GLOBAL_AS(agp1), LDS_AS(lA1), 16, 0, 0);
        __builtin_amdgcn_global_load_lds(GLOBAL_AS(bgp0), LDS_AS(lB0), 16, 0, 0);
        __builtin_amdgcn_global_load_lds(GLOBAL_AS(bgp1), LDS_AS(lB1), 16, 0, 0);
        agp0 += BK; agp1 += BK; bgp0 += BK; bgp1 += BK;
        __syncthreads();

        bf16x8 af[4], bfr[4];
#pragma unroll
        for (int i = 0; i < 4; ++i)
            af[i] = *reinterpret_cast<const bf16x8*>(&As[(wm + i * 16 + lrow) * BK + quad * 8]);
#pragma unroll
        for (int j = 0; j < 4; ++j)
            bfr[j] = *reinterpret_cast<const bf16x8*>(&Bs[(wn + j * 16 + lrow) * BK + quad * 8]);
#pragma unroll
        for (int i = 0; i < 4; ++i)
#pragma unroll
            for (int j = 0; j < 4; ++j)
                acc[i][j] = __builtin_amdgcn_mfma_f32_16x16x32_bf16(af[i], bfr[j], acc[i][j], 0, 0, 0);
    }

    // epilogue: C/D layout col=lane&15, row=quad*4+reg  [m89-verified]
#pragma unroll
    for (int i = 0; i < 4; ++i) {
        const int row = m0 + wm + i * 16 + quad * 4;
#pragma unroll
        for (int j = 0; j < 4; ++j) {
            const int col = n0 + wn + j * 16 + lrow;
            float badd = ADD_BIAS ? aux[col] : 0.0f;
#pragma unroll
            for (int v = 0; v < 4; ++v) {
                float val = acc[i][j][v] + badd;
                if (ADD_C) val += aux[(size_t)(row + v) * N + col];
                if (OUT_F32)
                    ((float*)OutP)[(size_t)(row + v) * N + col] = val;
                else
                    ((ushort*)OutP)[(size_t)(row + v) * N + col] = f2b(val);
            }
        }
    }
}

// ---------------------------------------------------------------------------
// tier-2 main GEMM (ws too small for xb): A is fp32, converted in-kernel via
// VGPR loads + ds_write; B (Weff bf16) via global_load_lds. fp32 out + bias.
// ---------------------------------------------------------------------------
__global__ __launch_bounds__(256) void gemm_af32(
    const float* __restrict__ Af, const ushort* __restrict__ Bmat,
    const float* __restrict__ bias, float* __restrict__ Out,
    int M, int N, int K)
{
    constexpr int BM = 128, BN = 128, BK = 32;
    __shared__ __align__(16) ushort As[BM * BK];
    __shared__ __align__(16) ushort Bs[BN * BK];

    const int tid  = threadIdx.x;
    const int lane = tid & 63;
    const int w    = tid >> 6;
    const int wm   = (w >> 1) * 64;
    const int wn   = (w & 1) * 64;
    const int quad = lane >> 4;
    const int lrow = lane & 15;
    const int m0 = blockIdx.x * BM;
    const int n0 = blockIdx.y * BN;

    const int srow = (w * 2) * 16 + (lane >> 2);
    const int kofs = (lane & 3) * 8;
    const ushort* bgp0 = Bmat + (size_t)(n0 + srow) * K + kofs;
    const ushort* bgp1 = bgp0 + (size_t)16 * K;
    ushort* lB0 = &Bs[(w * 2) * 512];
    ushort* lB1 = &Bs[(w * 2 + 1) * 512];

    f32x4 acc[4][4] = {};
    const int nK = K / BK;
    for (int kt = 0; kt < nK; ++kt) {
        __syncthreads();
        __builtin_amdgcn_global_load_lds(GLOBAL_AS(bgp0), LDS_AS(lB0), 16, 0, 0);
        __builtin_amdgcn_global_load_lds(GLOBAL_AS(bgp1), LDS_AS(lB1), 16, 0, 0);
        bgp0 += BK; bgp1 += BK;
#pragma unroll
        for (int gg = 0; gg < 2; ++gg) {
            int g = tid + gg * 256;            // 512 groups of 8 elems
            int row = g >> 2, kc = (g & 3) * 8;
            const float* src = Af + (size_t)(m0 + row) * K + (size_t)kt * BK + kc;
            float4 a = *(const float4*)src;
            float4 b = *(const float4*)(src + 4);
            u16x8 r;
            r[0] = f2b(a.x); r[1] = f2b(a.y); r[2] = f2b(a.z); r[3] = f2b(a.w);
            r[4] = f2b(b.x); r[5] = f2b(b.y); r[6] = f2b(b.z); r[7] = f2b(b.w);
            *reinterpret_cast<u16x8*>(&As[row * BK + kc]) = r;
        }
        __syncthreads();

        bf16x8 af[4], bfr[4];
#pragma unroll
        for (int i = 0; i < 4; ++i)
            af[i] = *reinterpret_cast<const bf16x8*>(&As[(wm + i * 16 + lrow) * BK + quad * 8]);
#pragma unroll
        for (int j = 0; j < 4; ++j)
            bfr[j] = *reinterpret_cast<const bf16x8*>(&Bs[(wn + j * 16 + lrow) * BK + quad * 8]);
#pragma unroll
        for (int i = 0; i < 4; ++i)
#pragma unroll
            for (int j = 0; j < 4; ++j)
                acc[i][j] = __builtin_amdgcn_mfma_f32_16x16x32_bf16(af[i], bfr[j], acc[i][j], 0, 0, 0);
    }

#pragma unroll
    for (int i = 0; i < 4; ++i) {
        const int row = m0 + wm + i * 16 + quad * 4;
#pragma unroll
        for (int j = 0; j < 4; ++j) {
            const int col = n0 + wn + j * 16 + lrow;
            float badd = bias[col];
#pragma unroll
            for (int v = 0; v < 4; ++v)
                Out[(size_t)(row + v) * N + col] = acc[i][j][v] + badd;
        }
    }
}

// ---------------------------------------------------------------------------
// emergency fallback (tiny ws): pure fp32, slow but correct
// ---------------------------------------------------------------------------
__global__ void naive_kernel(const float* __restrict__ x, const float* __restrict__ lA,
                             const float* __restrict__ lB, const float* __restrict__ W,
                             const float* __restrict__ bias, const float* __restrict__ lw,
                             float* __restrict__ out)
{
    __shared__ float xs[4096];
    __shared__ float h[128];
    const int m = blockIdx.x;
    for (int d = threadIdx.x; d < 4096; d += 256)
        xs[d] = x[(size_t)m * 4096 + d];
    __syncthreads();
    for (int k = threadIdx.x; k < 128; k += 256) {
        const float* arow = lA + (size_t)k * 4096;
        float s = 0.f;
        for (int d = 0; d < 4096; ++d) s += xs[d] * arow[d];
        h[k] = s;
    }
    __syncthreads();
    for (int o = threadIdx.x; o < 4096; o += 256) {
        const float* wrow = W + (size_t)o * 4096;
        float s = bias[o];
        for (int d = 0; d < 4096; ++d) s += xs[d] * wrow[d];
        for (int n = 0; n < 8; ++n) {
            const float* brow = lB + ((size_t)n * 4096 + o) * 16;
            float t = 0.f;
            for (int r = 0; r < 16; ++r) t += h[n * 16 + r] * brow[r];
            s += 2.0f * lw[n] * t;
        }
        out[(size_t)m * 4096 + o] = s;
    }
}

// ---------------------------------------------------------------------------
extern "C" void kernel_launch(void* const* d_in, const int* in_sizes, int n_in,
                              void* d_out, int out_size, void* d_ws, size_t ws_size,
                              hipStream_t stream)
{
    const float* x    = (const float*)d_in[0];  // [4,2048,4096]
    const float* lA   = (const float*)d_in[1];  // [8,16,4096]
    const float* lB   = (const float*)d_in[2];  // [8,4096,16]
    const float* W    = (const float*)d_in[3];  // [4096,4096]
    const float* bias = (const float*)d_in[4];  // [4096]
    const float* lw   = (const float*)d_in[5];  // [8]
    float* out = (float*)d_out;                 // [8192,4096] fp32

    // ws layout (bf16): [Bcat 1MiB][AcatT 1MiB][Weff 32MiB][xb 64MiB]
    ushort* Bcat  = (ushort*)d_ws;
    ushort* AcatT = Bcat + (size_t)4096 * 128;
    ushort* Weff  = AcatT + (size_t)4096 * 128;
    ushort* xb    = Weff + (size_t)4096 * 4096;
    const size_t need_t2 = (2 * (size_t)4096 * 128 + (size_t)4096 * 4096) * 2;
    const size_t need_t1 = need_t2 + (size_t)8192 * 4096 * 2;

    if (ws_size >= need_t2) {
        prep_kernel<<<2048, 256, 0, stream>>>(lA, lB, lw, Bcat, AcatT);
        // Weff[o][d] = W[o][d] + Bcat[o][:]·AcatT[d][:]   (bf16 out)
        gemm_bt<false, false, true><<<dim3(32, 32), 256, 0, stream>>>(
            Bcat, AcatT, W, Weff, 4096, 4096, 128);
        if (ws_size >= need_t1) {
            cvtx_kernel<<<16384, 256, 0, stream>>>(x, xb);
            // out[m][o] = xb[m][:]·Weff[o][:] + bias[o]   (fp32 out)
            gemm_bt<true, true, false><<<dim3(64, 32), 256, 0, stream>>>(
                xb, Weff, bias, out, 8192, 4096, 4096);
        } else {
            gemm_af32<<<dim3(64, 32), 256, 0, stream>>>(
                x, Weff, bias, out, 8192, 4096, 4096);
        }
    } else {
        naive_kernel<<<8192, 256, 0, stream>>>(x, lA, lB, W, bias, lw, out);
    }
}

// Round 4
// 650.428 us; speedup vs baseline: 1.0076x; 1.0076x over previous
//
#include <hip/hip_runtime.h>
#include <hip/hip_bf16.h>
#include <stdint.h>

// compose_lora (fp32 in / fp32 out):
//   out = x@W^T + bias + sum_n (SCALE*w_n) * (x@A_n^T)@B_n^T
// Factored: W_eff = W + sum_n c_n * B_n@A_n  (K=128 MFMA GEMM, bf16),
// then out = x_bf16 @ W_eff^T + bias  (M=8192,N=4096,K=4096).
// R3: passed, absmax 0.031. Main GEMM 398us (690 TF), aux ~257us.
// R4 changes: (a) K-loop stages 2x BK=32 buffer-pairs per barrier pair
// (halves barrier-drain stalls, LDS 32KB, layout unchanged); (b) coalesced
// LDS-tiled transpose in prep (old version did stride-16KB gathers).

typedef __attribute__((ext_vector_type(4))) float f32x4;
typedef __attribute__((ext_vector_type(8))) __bf16 bf16x8;
typedef __attribute__((ext_vector_type(8))) unsigned short u16x8;

#define GLOBAL_AS(p) ((const __attribute__((address_space(1))) void*)(p))
#define LDS_AS(p)    ((__attribute__((address_space(3))) void*)(p))

__device__ __forceinline__ ushort f2b(float f) {
    __hip_bfloat16 h = __float2bfloat16(f);
    ushort u;
    __builtin_memcpy(&u, &h, 2);
    return u;
}

// ---------------------------------------------------------------------------
// prep_a: AcatT[d][k] = bf16(lA[k][d])  — coalesced via LDS tile transpose.
// lA: [128][4096] fp32. Grid: 64 blocks, each handles 64 d-columns.
// ---------------------------------------------------------------------------
__global__ __launch_bounds__(256) void prep_a_kernel(const float* __restrict__ lA,
                                                     ushort* __restrict__ AcatT) {
    __shared__ ushort tile[64][136];   // +8 pad: no write-bank pathologies
    const int tid = threadIdx.x;
    const int d0 = blockIdx.x * 64;
    // phase 1: read lA rows coalesced (64 consecutive d per 64 lanes)
#pragma unroll
    for (int it = 0; it < 32; ++it) {
        int k = it * 4 + (tid >> 6);           // 0..127
        int dc = tid & 63;
        tile[dc][k] = f2b(lA[(size_t)k * 4096 + d0 + dc]);
    }
    __syncthreads();
    // phase 2: write AcatT rows coalesced (16B per thread, consecutive)
#pragma unroll
    for (int it = 0; it < 4; ++it) {
        int g = it * 256 + tid;                // 0..1023
        int dc = g >> 4, slot = g & 15;
        u16x8 v;
#pragma unroll
        for (int e = 0; e < 8; ++e) v[e] = tile[dc][slot * 8 + e];
        *reinterpret_cast<u16x8*>(&AcatT[((size_t)(d0 + dc)) * 128 + slot * 8]) = v;
    }
}

// ---------------------------------------------------------------------------
// prep_b: Bcat[o][k] = bf16( (2*lw[k/16]) * lora_B[k/16][o][k%16] )
// (SCALE = ALPHA/RANK = 2; coef_n = SCALE * lora_weights[n])
// ---------------------------------------------------------------------------
__global__ void prep_b_kernel(const float* __restrict__ lB,  // [8][4096][16]
                              const float* __restrict__ lw,  // [8]
                              ushort* __restrict__ Bcat)     // [4096][128]
{
    int idx = blockIdx.x * 256 + threadIdx.x;   // 0..524287 exact
    int o = idx >> 7, k = idx & 127;
    int n = k >> 4, r = k & 15;
    Bcat[idx] = f2b(2.0f * lw[n] * lB[((size_t)n * 4096 + o) * 16 + r]);
}

// ---------------------------------------------------------------------------
// cvtx: x fp32 -> bf16 workspace copy
// ---------------------------------------------------------------------------
__global__ void cvtx_kernel(const float* __restrict__ x, ushort* __restrict__ xb) {
    size_t i = ((size_t)blockIdx.x * 256 + threadIdx.x) * 8;
    const float4* xf = (const float4*)(x + i);
    float4 a = xf[0], b = xf[1];
    u16x8 r;
    r[0] = f2b(a.x); r[1] = f2b(a.y); r[2] = f2b(a.z); r[3] = f2b(a.w);
    r[4] = f2b(b.x); r[5] = f2b(b.y); r[6] = f2b(b.z); r[7] = f2b(b.w);
    *reinterpret_cast<u16x8*>(xb + i) = r;
}

// ---------------------------------------------------------------------------
// bf16 GEMM: Out[M][N] = A[M][K]*B[N][K]^T (+bias[n] / +C[m][n])
// 128x128 tile, 4 waves, 4x4 mfma_f32_16x16x32_bf16 per wave.
// K-loop: 2x BK=32 buffer-pairs staged per barrier pair (K-step 64).
// K must be a multiple of 64.
// ---------------------------------------------------------------------------
template <bool OUT_F32, bool ADD_BIAS, bool ADD_C>
__global__ __launch_bounds__(256) void gemm_bt(
    const ushort* __restrict__ Amat, const ushort* __restrict__ Bmat,
    const float* __restrict__ aux, void* __restrict__ OutP,
    int M, int N, int K)
{
    constexpr int BK = 32;
    __shared__ __align__(16) ushort As[2 * 128 * BK];   // [buf][128][32]
    __shared__ __align__(16) ushort Bs[2 * 128 * BK];

    const int tid  = threadIdx.x;
    const int lane = tid & 63;
    const int w    = tid >> 6;
    const int wm   = (w >> 1) * 64;
    const int wn   = (w & 1) * 64;
    const int quad = lane >> 4;
    const int lrow = lane & 15;
    const int m0 = blockIdx.x * 128;
    const int n0 = blockIdx.y * 128;

    // staging: wave w fills chunks {2w,2w+1}; lane l -> row 16c+l/4, k=(l%4)*8
    const int srow = (w * 2) * 16 + (lane >> 2);
    const int kofs = (lane & 3) * 8;
    const ushort* agp0 = Amat + (size_t)(m0 + srow) * K + kofs;
    const ushort* agp1 = agp0 + (size_t)16 * K;
    const ushort* bgp0 = Bmat + (size_t)(n0 + srow) * K + kofs;
    const ushort* bgp1 = bgp0 + (size_t)16 * K;
    ushort* lA00 = &As[(w * 2) * 512];
    ushort* lA01 = &As[(w * 2 + 1) * 512];
    ushort* lB00 = &Bs[(w * 2) * 512];
    ushort* lB01 = &Bs[(w * 2 + 1) * 512];

    f32x4 acc[4][4] = {};
    const int nK = K >> 6;              // K/64
    for (int kt = 0; kt < nK; ++kt) {
        __syncthreads();
        __builtin_amdgcn_global_load_lds(GLOBAL_AS(agp0),      LDS_AS(lA00),        16, 0, 0);
        __builtin_amdgcn_global_load_lds(GLOBAL_AS(agp1),      LDS_AS(lA01),        16, 0, 0);
        __builtin_amdgcn_global_load_lds(GLOBAL_AS(agp0 + 32), LDS_AS(lA00 + 4096), 16, 0, 0);
        __builtin_amdgcn_global_load_lds(GLOBAL_AS(agp1 + 32), LDS_AS(lA01 + 4096), 16, 0, 0);
        __builtin_amdgcn_global_load_lds(GLOBAL_AS(bgp0),      LDS_AS(lB00),        16, 0, 0);
        __builtin_amdgcn_global_load_lds(GLOBAL_AS(bgp1),      LDS_AS(lB01),        16, 0, 0);
        __builtin_amdgcn_global_load_lds(GLOBAL_AS(bgp0 + 32), LDS_AS(lB00 + 4096), 16, 0, 0);
        __builtin_amdgcn_global_load_lds(GLOBAL_AS(bgp1 + 32), LDS_AS(lB01 + 4096), 16, 0, 0);
        agp0 += 64; agp1 += 64; bgp0 += 64; bgp1 += 64;
        __syncthreads();

#pragma unroll
        for (int h = 0; h < 2; ++h) {
            const ushort* ab = &As[h * 4096];
            const ushort* bb = &Bs[h * 4096];
            bf16x8 af[4], bfr[4];
#pragma unroll
            for (int i = 0; i < 4; ++i)
                af[i] = *reinterpret_cast<const bf16x8*>(&ab[(wm + i * 16 + lrow) * BK + quad * 8]);
#pragma unroll
            for (int j = 0; j < 4; ++j)
                bfr[j] = *reinterpret_cast<const bf16x8*>(&bb[(wn + j * 16 + lrow) * BK + quad * 8]);
#pragma unroll
            for (int i = 0; i < 4; ++i)
#pragma unroll
                for (int j = 0; j < 4; ++j)
                    acc[i][j] = __builtin_amdgcn_mfma_f32_16x16x32_bf16(af[i], bfr[j], acc[i][j], 0, 0, 0);
        }
    }

    // epilogue: C/D layout col=lane&15, row=quad*4+reg  [m89-verified]
#pragma unroll
    for (int i = 0; i < 4; ++i) {
        const int row = m0 + wm + i * 16 + quad * 4;
#pragma unroll
        for (int j = 0; j < 4; ++j) {
            const int col = n0 + wn + j * 16 + lrow;
            float badd = ADD_BIAS ? aux[col] : 0.0f;
#pragma unroll
            for (int v = 0; v < 4; ++v) {
                float val = acc[i][j][v] + badd;
                if (ADD_C) val += aux[(size_t)(row + v) * N + col];
                if (OUT_F32)
                    ((float*)OutP)[(size_t)(row + v) * N + col] = val;
                else
                    ((ushort*)OutP)[(size_t)(row + v) * N + col] = f2b(val);
            }
        }
    }
}

// ---------------------------------------------------------------------------
// tier-2 main GEMM (ws too small for xb): A fp32 converted in-kernel.
// ---------------------------------------------------------------------------
__global__ __launch_bounds__(256) void gemm_af32(
    const float* __restrict__ Af, const ushort* __restrict__ Bmat,
    const float* __restrict__ bias, float* __restrict__ Out,
    int M, int N, int K)
{
    constexpr int BM = 128, BN = 128, BK = 32;
    __shared__ __align__(16) ushort As[BM * BK];
    __shared__ __align__(16) ushort Bs[BN * BK];

    const int tid  = threadIdx.x;
    const int lane = tid & 63;
    const int w    = tid >> 6;
    const int wm   = (w >> 1) * 64;
    const int wn   = (w & 1) * 64;
    const int quad = lane >> 4;
    const int lrow = lane & 15;
    const int m0 = blockIdx.x * BM;
    const int n0 = blockIdx.y * BN;

    const int srow = (w * 2) * 16 + (lane >> 2);
    const int kofs = (lane & 3) * 8;
    const ushort* bgp0 = Bmat + (size_t)(n0 + srow) * K + kofs;
    const ushort* bgp1 = bgp0 + (size_t)16 * K;
    ushort* lB0 = &Bs[(w * 2) * 512];
    ushort* lB1 = &Bs[(w * 2 + 1) * 512];

    f32x4 acc[4][4] = {};
    const int nK = K / BK;
    for (int kt = 0; kt < nK; ++kt) {
        __syncthreads();
        __builtin_amdgcn_global_load_lds(GLOBAL_AS(bgp0), LDS_AS(lB0), 16, 0, 0);
        __builtin_amdgcn_global_load_lds(GLOBAL_AS(bgp1), LDS_AS(lB1), 16, 0, 0);
        bgp0 += BK; bgp1 += BK;
#pragma unroll
        for (int gg = 0; gg < 2; ++gg) {
            int g = tid + gg * 256;
            int row = g >> 2, kc = (g & 3) * 8;
            const float* src = Af + (size_t)(m0 + row) * K + (size_t)kt * BK + kc;
            float4 a = *(const float4*)src;
            float4 b = *(const float4*)(src + 4);
            u16x8 r;
            r[0] = f2b(a.x); r[1] = f2b(a.y); r[2] = f2b(a.z); r[3] = f2b(a.w);
            r[4] = f2b(b.x); r[5] = f2b(b.y); r[6] = f2b(b.z); r[7] = f2b(b.w);
            *reinterpret_cast<u16x8*>(&As[row * BK + kc]) = r;
        }
        __syncthreads();

        bf16x8 af[4], bfr[4];
#pragma unroll
        for (int i = 0; i < 4; ++i)
            af[i] = *reinterpret_cast<const bf16x8*>(&As[(wm + i * 16 + lrow) * BK + quad * 8]);
#pragma unroll
        for (int j = 0; j < 4; ++j)
            bfr[j] = *reinterpret_cast<const bf16x8*>(&Bs[(wn + j * 16 + lrow) * BK + quad * 8]);
#pragma unroll
        for (int i = 0; i < 4; ++i)
#pragma unroll
            for (int j = 0; j < 4; ++j)
                acc[i][j] = __builtin_amdgcn_mfma_f32_16x16x32_bf16(af[i], bfr[j], acc[i][j], 0, 0, 0);
    }

#pragma unroll
    for (int i = 0; i < 4; ++i) {
        const int row = m0 + wm + i * 16 + quad * 4;
#pragma unroll
        for (int j = 0; j < 4; ++j) {
            const int col = n0 + wn + j * 16 + lrow;
            float badd = bias[col];
#pragma unroll
            for (int v = 0; v < 4; ++v)
                Out[(size_t)(row + v) * N + col] = acc[i][j][v] + badd;
        }
    }
}

// ---------------------------------------------------------------------------
// emergency fallback (tiny ws): pure fp32, slow but correct
// ---------------------------------------------------------------------------
__global__ void naive_kernel(const float* __restrict__ x, const float* __restrict__ lA,
                             const float* __restrict__ lB, const float* __restrict__ W,
                             const float* __restrict__ bias, const float* __restrict__ lw,
                             float* __restrict__ out)
{
    __shared__ float xs[4096];
    __shared__ float h[128];
    const int m = blockIdx.x;
    for (int d = threadIdx.x; d < 4096; d += 256)
        xs[d] = x[(size_t)m * 4096 + d];
    __syncthreads();
    for (int k = threadIdx.x; k < 128; k += 256) {
        const float* arow = lA + (size_t)k * 4096;
        float s = 0.f;
        for (int d = 0; d < 4096; ++d) s += xs[d] * arow[d];
        h[k] = s;
    }
    __syncthreads();
    for (int o = threadIdx.x; o < 4096; o += 256) {
        const float* wrow = W + (size_t)o * 4096;
        float s = bias[o];
        for (int d = 0; d < 4096; ++d) s += xs[d] * wrow[d];
        for (int n = 0; n < 8; ++n) {
            const float* brow = lB + ((size_t)n * 4096 + o) * 16;
            float t = 0.f;
            for (int r = 0; r < 16; ++r) t += h[n * 16 + r] * brow[r];
            s += 2.0f * lw[n] * t;
        }
        out[(size_t)m * 4096 + o] = s;
    }
}

// ---------------------------------------------------------------------------
extern "C" void kernel_launch(void* const* d_in, const int* in_sizes, int n_in,
                              void* d_out, int out_size, void* d_ws, size_t ws_size,
                              hipStream_t stream)
{
    const float* x    = (const float*)d_in[0];  // [4,2048,4096]
    const float* lA   = (const float*)d_in[1];  // [8,16,4096]
    const float* lB   = (const float*)d_in[2];  // [8,4096,16]
    const float* W    = (const float*)d_in[3];  // [4096,4096]
    const float* bias = (const float*)d_in[4];  // [4096]
    const float* lw   = (const float*)d_in[5];  // [8]
    float* out = (float*)d_out;                 // [8192,4096] fp32

    // ws layout (bf16): [Bcat 1MiB][AcatT 1MiB][Weff 32MiB][xb 64MiB]
    ushort* Bcat  = (ushort*)d_ws;
    ushort* AcatT = Bcat + (size_t)4096 * 128;
    ushort* Weff  = AcatT + (size_t)4096 * 128;
    ushort* xb    = Weff + (size_t)4096 * 4096;
    const size_t need_t2 = (2 * (size_t)4096 * 128 + (size_t)4096 * 4096) * 2;
    const size_t need_t1 = need_t2 + (size_t)8192 * 4096 * 2;

    if (ws_size >= need_t2) {
        prep_a_kernel<<<64, 256, 0, stream>>>(lA, AcatT);
        prep_b_kernel<<<2048, 256, 0, stream>>>(lB, lw, Bcat);
        // Weff[o][d] = W[o][d] + Bcat[o][:]·AcatT[d][:]   (bf16 out, K=128)
        gemm_bt<false, false, true><<<dim3(32, 32), 256, 0, stream>>>(
            Bcat, AcatT, W, Weff, 4096, 4096, 128);
        if (ws_size >= need_t1) {
            cvtx_kernel<<<16384, 256, 0, stream>>>(x, xb);
            // out[m][o] = xb[m][:]·Weff[o][:] + bias[o]   (fp32 out)
            gemm_bt<true, true, false><<<dim3(64, 32), 256, 0, stream>>>(
                xb, Weff, bias, out, 8192, 4096, 4096);
        } else {
            gemm_af32<<<dim3(64, 32), 256, 0, stream>>>(
                x, Weff, bias, out, 8192, 4096, 4096);
        }
    } else {
        naive_kernel<<<8192, 256, 0, stream>>>(x, lA, lB, W, bias, lw, out);
    }
}